// Round 9
// baseline (67.970 us; speedup 1.0000x reference)
//
#include <hip/hip_runtime.h>
#include <hip/hip_bf16.h>
#include <stdint.h>

// C[4096,10532] = inputs[4096,256] @ concat(lut,queue)[10532,256]^T  (fp32 out)
// R9: STRIP-MINED R6. Each block computes 4 m-tiles (128x128 each) at a fixed
// bn: K-loop(tile) -> store(tile) -> K-loop(next) ... Stores issue at 4 spread
// points and drain in the background of the next tile's staging/compute,
// instead of one end-of-kernel burst synchronized across the whole grid.
// grid = 664 = 8 XCD chunks x 83 bn; XCD x owns m-rows 4x..4x+3 (one 512-row
// A band = 256 KB L2-resident per XCD; C written as one contiguous band).

#define M_DIM 4096
#define K_DIM 256
#define N_LUT 5532
#define N_Q   5000
#define N_DIM (N_LUT + N_Q)   // 10532
#define NT_M  32              // 4096/128
#define NT_N  83              // ceil(10532/128)
#define N_PAD (NT_N * 128)    // 10624

typedef _Float16 f16x8 __attribute__((ext_vector_type(8)));
typedef float f32x4 __attribute__((ext_vector_type(4)));

__device__ __forceinline__ unsigned short f2h(float f) {
  union { _Float16 h; unsigned short u; } v;
  v.h = (_Float16)f;   // v_cvt_f16_f32, RNE
  return v.u;
}

// ---------------- convert fp32 -> f16 into workspace ----------------
__global__ __launch_bounds__(256) void convert_kernel(
    const float* __restrict__ inp, const float* __restrict__ lut,
    const float* __restrict__ que, unsigned short* __restrict__ Abf,
    unsigned short* __restrict__ Bbf) {
  const int AV = M_DIM * K_DIM / 4;  // 262144 float4s for A
  int i = blockIdx.x * 256 + threadIdx.x;  // grid sized exactly
  float4 x;
  unsigned short* dst;
  if (i < AV) {
    x = ((const float4*)inp)[i];
    dst = Abf + i * 4;
  } else {
    int e = (i - AV) * 4;          // element index in padded B
    int row = e >> 8;              // /256
    int col = e & 255;
    if (row < N_LUT)
      x = *(const float4*)(lut + (size_t)row * K_DIM + col);
    else if (row < N_DIM)
      x = *(const float4*)(que + (size_t)(row - N_LUT) * K_DIM + col);
    else
      x = make_float4(0.f, 0.f, 0.f, 0.f);
    dst = Bbf + e;
  }
  ushort4 o;
  o.x = f2h(x.x); o.y = f2h(x.y); o.z = f2h(x.z); o.w = f2h(x.w);
  *(ushort4*)dst = o;
}

// ---------------- GEMM: C = A * B^T, both [rows][K] f16 ----------------
#define GLDS16(gsrc, ldst)                                                  \
  __builtin_amdgcn_global_load_lds(                                         \
      (__attribute__((address_space(1))) void*)(gsrc),                      \
      (__attribute__((address_space(3))) void*)(ldst), 16, 0, 0)

__global__ __launch_bounds__(256, 2) void gemm_kernel(
    const unsigned short* __restrict__ A, const unsigned short* __restrict__ B,
    float* __restrict__ C) {
  // single-buffered 128x64 f16 tiles: 32 KB total
  __shared__ __align__(16) unsigned short As[128 * 64];
  __shared__ __align__(16) unsigned short Bs[128 * 64];

  const int t = threadIdx.x;
  const int lane = t & 63;
  const int wave = t >> 6;         // 4 waves
  const int wm = wave >> 1;        // 2x2 wave grid, each 64x64 output
  const int wn = wave & 1;

  // grid = 664 = 8 * 83. XCD chunk x = blocks with bid&7==x; within a chunk,
  // consecutive blocks are bn-neighbors in the SAME 512-row m-band.
  int bid = blockIdx.x;
  const int s = bid & 7;           // m-band: m-tiles 4s..4s+3
  const int bn = bid >> 3;         // 0..82
  const int bcol = bn * 128;

  // staging geometry with PRE-SWIZZLED global source (LDS dest linear):
  // lds[row][ch] = global[row][ch ^ (row&7)] (16B chunks)
  const int trow = t >> 3;                       // 0..31
  const int tcs = (((t & 7) ^ (trow & 7)) * 8);  // swizzled col, elements
  const unsigned short* gbBase = B + (size_t)(bcol + trow) * K_DIM + tcs;
  const int ldsOff = wave * 512;   // elements; HW adds lane*16 bytes

#define STAGE(ga, kt)                                                        \
  do {                                                                       \
    _Pragma("unroll") for (int is = 0; is < 4; ++is) {                       \
      GLDS16((ga) + (size_t)is * 32 * K_DIM + (kt) * 64,                     \
             As + is * 2048 + ldsOff);                                       \
      GLDS16(gbBase + (size_t)is * 32 * K_DIM + (kt) * 64,                   \
             Bs + is * 2048 + ldsOff);                                       \
    }                                                                        \
  } while (0)

  const int lr = lane & 15;
  const int rsw = lane & 7;        // = row&7 for all fragment rows
  const int cq = lane >> 4;        // quarter-wave id = base col chunk
  const int cc4 = cq * 4;

#pragma unroll 1                   // keep the 4 m-tiles as a compact loop
  for (int mt = 0; mt < 4; ++mt) {
    const int brow = (s * 4 + mt) * 128;
    const unsigned short* gaBase = A + (size_t)(brow + trow) * K_DIM + tcs;

    f32x4 acc[4][4];
#pragma unroll
    for (int i = 0; i < 4; ++i)
#pragma unroll
      for (int j = 0; j < 4; ++j) acc[i][j] = (f32x4){0.f, 0.f, 0.f, 0.f};

#pragma unroll
    for (int kt = 0; kt < 4; ++kt) { // K = 256 = 4 * 64
      STAGE(gaBase, kt);
      __syncthreads();               // vmcnt(0)+lgkmcnt(0) drain + barrier

#pragma unroll
      for (int kk = 0; kk < 64; kk += 32) {
        const int ch = ((kk >> 3) + cq) ^ rsw;   // swizzled 16B chunk
        f16x8 b[4];
#pragma unroll
        for (int j = 0; j < 4; ++j)
          b[j] = *(const f16x8*)&Bs[(wn * 64 + j * 16 + lr) * 64 + ch * 8];
#pragma unroll
        for (int i = 0; i < 4; ++i) {
          f16x8 a = *(const f16x8*)&As[(wm * 64 + i * 16 + lr) * 64 + ch * 8];
          // swapped operands: C-row = i*16+lr, C-cols = j*16 + cc4 + reg
#pragma unroll
          for (int j = 0; j < 4; ++j)
            acc[i][j] = __builtin_amdgcn_mfma_f32_16x16x32_f16(b[j], a,
                                                               acc[i][j], 0, 0, 0);
        }
      }
      __syncthreads();               // all waves done reading before next STAGE
    }

    // store this m-tile NOW; stores read acc at issue and drain in the
    // background of the next m-tile's staging/compute (no wait here).
#pragma unroll
    for (int i = 0; i < 4; ++i) {
      size_t rowBase = (size_t)(brow + wm * 64 + i * 16 + lr) * N_DIM;
#pragma unroll
      for (int j = 0; j < 4; ++j) {
        int col = bcol + wn * 64 + j * 16 + cc4;
        if (col < N_DIM)
          *(f32x4*)&C[rowBase + col] = acc[i][j];
      }
    }
  }
#undef STAGE
}

extern "C" void kernel_launch(void* const* d_in, const int* in_sizes, int n_in,
                              void* d_out, int out_size, void* d_ws, size_t ws_size,
                              hipStream_t stream) {
  const float* inp = (const float*)d_in[0];   // inputs [4096,256]
  // d_in[1] targets, d_in[2] gt_flag: unused by the forward similarity
  const float* lut = (const float*)d_in[3];   // [5532,256]
  const float* que = (const float*)d_in[4];   // [5000,256]
  float* C = (float*)d_out;                   // [4096,10532]

  unsigned short* Abf = (unsigned short*)d_ws;
  unsigned short* Bbf = Abf + (size_t)M_DIM * K_DIM;  // ~7.6 MB of ws

  const int conv_blocks = (M_DIM * K_DIM / 4 + N_PAD * K_DIM / 4) / 256;
  convert_kernel<<<conv_blocks, 256, 0, stream>>>(inp, lut, que, Abf, Bbf);

  gemm_kernel<<<8 * NT_N, 256, 0, stream>>>(Abf, Bbf, C);
}